// Round 6
// baseline (697.304 us; speedup 1.0000x reference)
//
#include <hip/hip_runtime.h>

#define BB 16
#define NNN 1024
#define CC 768
#define HH 12
#define DD 64
#define HIDN 3072
#define ROWS (BB*NNN)   // 16384

typedef _Float16 half8 __attribute__((ext_vector_type(8)));
typedef _Float16 half4 __attribute__((ext_vector_type(4)));
typedef float floatx4 __attribute__((ext_vector_type(4)));

#define MFMA16(acc_, a_, b_) acc_ = __builtin_amdgcn_mfma_f32_16x16x32_f16(a_, b_, acc_, 0, 0, 0)

// ---------------- weight fp32 -> fp16 convert ----------------
__global__ void cvt_kernel(const float* __restrict__ src, _Float16* __restrict__ dst, int n4) {
    int i = blockIdx.x * blockDim.x + threadIdx.x;
    if (i < n4) {
        floatx4 v = ((const floatx4*)src)[i];
        half4 h;
        h[0] = (_Float16)v[0]; h[1] = (_Float16)v[1];
        h[2] = (_Float16)v[2]; h[3] = (_Float16)v[3];
        ((half4*)dst)[i] = h;
    }
}

// ---------------- head compaction ----------------
// gate_h: sigmoid>0.5 <=> gh>0; ~half the 12 heads are hard-masked.  Build
// order-preserving active-head perm.  hmeta[0]=3*Hpad*64 (QKV N bound),
// hmeta[1]=Ha, hmeta[2]=Hpad*64 (segment width), Hpad = Ha rounded up to even.
__global__ void scanh_kernel(const float* __restrict__ gh, int* __restrict__ hmeta,
                             int* __restrict__ hperm) {
    if (threadIdx.x == 0 && blockIdx.x == 0) {
        int c = 0;
        for (int i = 0; i < HH; i++) if (gh[i] > 0.0f) hperm[c++] = i;
        for (int i = c; i < HH; i++) hperm[i] = -1;
        int Hp = (c + 1) & ~1;
        hmeta[1] = c;
        hmeta[2] = Hp * 64;
        hmeta[0] = 3 * Hp * 64;
    }
}

// wq|wk|wv [768][768] f32 -> compacted fp16 [3*Hpad*64][768] (active heads only)
__global__ void gatherQKV_kernel(const float* __restrict__ wq, const float* __restrict__ wk,
                                 const float* __restrict__ wv, const int* __restrict__ hmeta,
                                 const int* __restrict__ hperm, _Float16* __restrict__ dst) {
    int i = blockIdx.x * blockDim.x + threadIdx.x;   // over 2304*192 float4 chunks
    int row = i / 192, c4 = i - row * 192;
    if (row >= hmeta[0]) return;
    int segw = hmeta[2];
    int seg = row / segw, rem = row - seg * segw;
    int ho = hperm[rem >> 6];
    half4 h; h[0] = h[1] = h[2] = h[3] = (_Float16)0.0f;
    if (ho >= 0) {
        const float* src = (seg == 0 ? wq : seg == 1 ? wk : wv) +
                           (size_t)(ho * 64 + (rem & 63)) * CC;
        floatx4 v = ((const floatx4*)src)[c4];
        h[0] = (_Float16)v[0]; h[1] = (_Float16)v[1];
        h[2] = (_Float16)v[2]; h[3] = (_Float16)v[3];
    }
    ((half4*)&dst[(size_t)row * CC])[c4] = h;
}

// ---------------- FFN channel compaction ----------------
// gate_f masks ~half the FFN channels to EXACT zero in F1.  Order-preserving
// perm of active channels + compacted bias.  meta[0]=Na_pad128, meta[1]=Na.
__global__ __launch_bounds__(256) void scan_kernel(const float* __restrict__ gf,
                                                   const float* __restrict__ b1,
                                                   int* __restrict__ meta,
                                                   int* __restrict__ perm,
                                                   float* __restrict__ b1c) {
    int t = threadIdx.x;            // 256 threads x 12 elems = 3072
    int base = t * 12;
    bool act[12];
    int cnt = 0;
    #pragma unroll
    for (int i = 0; i < 12; i++) { bool a = gf[base + i] > 0.0f; act[i] = a; cnt += a ? 1 : 0; }
    __shared__ int cs[256];
    cs[t] = cnt;
    __syncthreads();
    if (t == 0) {
        int s = 0;
        for (int i = 0; i < 256; i++) { int c = cs[i]; cs[i] = s; s += c; }
        meta[1] = s;
        meta[0] = (s + 127) & ~127;
    }
    __syncthreads();
    int off = cs[t];
    for (int i = t; i < HIDN; i += 256) { b1c[i] = 0.0f; perm[i] = -1; }
    __syncthreads();
    #pragma unroll
    for (int i = 0; i < 12; i++)
        if (act[i]) { perm[off] = base + i; b1c[off] = b1[base + i]; off++; }
}

// W1 [3072][768] f32 -> W1c: compacted rows (perm), fp16, zero pad rows
__global__ void gatherW1_kernel(const float* __restrict__ src, const int* __restrict__ perm,
                                _Float16* __restrict__ dst) {
    int i = blockIdx.x * blockDim.x + threadIdx.x;   // over 3072*192 float4 chunks
    int row = i / 192, c4 = i - row * 192;
    int s = perm[row];
    half4 h; h[0] = h[1] = h[2] = h[3] = (_Float16)0.0f;
    if (s >= 0) {
        floatx4 v = ((const floatx4*)(src + (size_t)s * CC))[c4];
        h[0] = (_Float16)v[0]; h[1] = (_Float16)v[1];
        h[2] = (_Float16)v[2]; h[3] = (_Float16)v[3];
    }
    ((half4*)dst)[i] = h;
}

// W2 [768][3072] f32 -> W2c: compacted COLUMNS (perm), fp16, zero pad cols
__global__ void gatherW2_kernel(const float* __restrict__ src, const int* __restrict__ perm,
                                _Float16* __restrict__ dst) {
    int i = blockIdx.x * blockDim.x + threadIdx.x;   // over 768*768 groups of 4 cols
    int n = i / 768, j4 = (i - n * 768) * 4;
    const float* r = src + (size_t)n * HIDN;
    half4 h;
    #pragma unroll
    for (int e = 0; e < 4; e++) {
        int s = perm[j4 + e];
        h[e] = (s >= 0) ? (_Float16)r[s] : (_Float16)0.0f;
    }
    *(half4*)&dst[(size_t)n * HIDN + j4] = h;
}

// ---------------- LayerNorm (row of 768), fp32 in -> fp16 out ----------------
__global__ __launch_bounds__(256) void ln_kernel(const float* __restrict__ x,
                                                 const float* __restrict__ g,
                                                 const float* __restrict__ b,
                                                 _Float16* __restrict__ out) {
    int row = blockIdx.x;
    int t = threadIdx.x;
    const float* xr = x + (size_t)row * CC;
    float v0 = xr[t], v1 = xr[t + 256], v2 = xr[t + 512];
    float s = v0 + v1 + v2;
    float q = v0 * v0 + v1 * v1 + v2 * v2;
    #pragma unroll
    for (int m = 1; m < 64; m <<= 1) {
        s += __shfl_xor(s, m, 64);
        q += __shfl_xor(q, m, 64);
    }
    __shared__ float red[8];
    int wv = t >> 6, lane = t & 63;
    if (lane == 0) { red[wv] = s; red[wv + 4] = q; }
    __syncthreads();
    s = red[0] + red[1] + red[2] + red[3];
    q = red[4] + red[5] + red[6] + red[7];
    float mean = s * (1.0f / CC);
    float var = q * (1.0f / CC) - mean * mean;
    float rs = rsqrtf(var + 1e-5f);
    _Float16* orow = out + (size_t)row * CC;
    orow[t]       = (_Float16)((v0 - mean) * rs * g[t]       + b[t]);
    orow[t + 256] = (_Float16)((v1 - mean) * rs * g[t + 256] + b[t + 256]);
    orow[t + 512] = (_Float16)((v2 - mean) * rs * g[t + 512] + b[t + 512]);
}

// ---------------- MFMA GEMM: ALL-REGISTER (no LDS, no barriers) -------------
// r5 post-mortem: per-block-step wall ~1570cy vs ~310cy MFMA — LDS BW bound
// (48KB LDS traffic per 128x128xBK32 step).  Fix: each wave loads its MFMA
// fragments DIRECTLY from global.  The fragment pattern (lane=quad*16+L reads
// row wm+i*16+L, 16B at k+quad*8) touches 16 full 64B lines per load — same
// line count as an ideal coalesced dwordx4 load, all bytes consumed.  A
// half-tiles shared by 2 waves -> L1 hits; B tiles L2/LLC-resident.  No
// __shared__, no barriers, no vmcnt: waves fully decoupled, compiler pipelines.
// Tile 128x128 per 4-wave block, each wave 64x64 (acc 4x4xf32x4).
// MODE 0: compacted QKV (meta=hmeta, hperm; epilogue scatters to orig heads)
// MODE 1: out fp16 = gelu(acc + bias0); meta[0] = compacted-FFN N bound
// MODE 2: out fp32 = res + acc + bias0; kmask (hgate) skips masked-head K; meta[0]=eff.K
template <int MODE>
__global__ __launch_bounds__(256) void gemm_kernel(
    const _Float16* __restrict__ A,
    const _Float16* __restrict__ W,
    const float* __restrict__ bias0,
    const float* __restrict__ bias1,
    const float* __restrict__ bias2,
    const float* __restrict__ res,
    const float* __restrict__ gate,
    const float* __restrict__ hgate,
    void* __restrict__ out0,
    void* __restrict__ out1,
    void* __restrict__ out2,
    const int* __restrict__ meta,
    const int* __restrict__ hperm,
    int M, int N, int K)
{
    // XCD-aware swizzle (GM=128 -> 16 m-stripes per XCD)
    int GN = N >> 7, GM = M >> 7;
    int f = blockIdx.x;
    int xcd = f & 7, slot = f >> 3;
    int m_idx = xcd * (GM >> 3) + slot / GN;
    int n_idx = slot - (slot / GN) * GN;
    int m0 = m_idx * 128, n0 = n_idx * 128;

    int Klen = K;
    if (MODE == 0) { if (n0 >= meta[0]) return; }       // compacted QKV width
    if (MODE == 1) { if (n0 >= meta[0]) return; }       // compacted FFN width
    if (MODE == 2 && meta) Klen = meta[0];              // compacted K sweep

    // K-block gate mask (proj: zero A-columns from masked heads), 64-k granularity
    unsigned kmask = 0xFFFFFFFFu;
    if (MODE == 2 && hgate) {
        kmask = 0;
        for (int i = 0; i < HH; i++) kmask |= (hgate[i] > 0.0f ? 1u : 0u) << i;
    }

    int t = threadIdx.x;
    int lane = t & 63, w = t >> 6;
    int wm = (w >> 1) * 64, wn = (w & 1) * 64;
    int L = lane & 15, quad = lane >> 4;

    floatx4 acc[4][4];
    #pragma unroll
    for (int i = 0; i < 4; i++)
        #pragma unroll
        for (int j = 0; j < 4; j++)
            acc[i][j] = (floatx4){0.f, 0.f, 0.f, 0.f};

    // per-lane fragment base pointers (16B each at k + quad*8)
    const _Float16* ap[4];
    const _Float16* bp[4];
    #pragma unroll
    for (int i = 0; i < 4; i++) ap[i] = A + (size_t)(m0 + wm + i * 16 + L) * K + quad * 8;
    #pragma unroll
    for (int j = 0; j < 4; j++) bp[j] = W + (size_t)(n0 + wn + j * 16 + L) * K + quad * 8;

    auto step = [&](int k) {
        half8 af[4], bf[4];
        #pragma unroll
        for (int i = 0; i < 4; i++) af[i] = *(const half8*)(ap[i] + k);
        #pragma unroll
        for (int j = 0; j < 4; j++) bf[j] = *(const half8*)(bp[j] + k);
        #pragma unroll
        for (int i = 0; i < 4; i++)
            #pragma unroll
            for (int j = 0; j < 4; j++)
                MFMA16(acc[i][j], af[i], bf[j]);
    };

    if (MODE == 2 && hgate) {
        // proj: skip masked-head 64-col blocks of K
        for (int k = 0; k < Klen; k += 32) {
            if (!((kmask >> ((k >> 6) & 31)) & 1)) continue;
            step(k);
        }
    } else {
        #pragma unroll 2
        for (int k = 0; k < Klen; k += 32) step(k);
    }

    // epilogue: C row = quad*4 + r (M side), col = L (N side)  [verified m89/m91 layout]
    if (MODE == 0) {
        int segw = meta[2];
        int seg = n0 / segw;
        int cbase = n0 - seg * segw + wn;   // head-col base within segment (mult of 64)
        int ho = hperm[cbase >> 6];         // orig head (uniform per wave)
        if (ho < 0) return;                 // pad head: outputs never read
        #pragma unroll
        for (int i = 0; i < 4; i++) {
            #pragma unroll
            for (int j = 0; j < 4; j++) {
                int d = j * 16 + L;         // 0..63 within head
                int ocol = ho * 64 + d;
                const float* bsel = (seg == 0) ? bias0 : (seg == 1) ? bias1 : bias2;
                float bs = bsel[ocol];
                if (seg < 2) {
                    _Float16* o = (_Float16*)((seg == 0) ? out0 : out1);
                    #pragma unroll
                    for (int r = 0; r < 4; r++) {
                        int gm = m0 + wm + i * 16 + quad * 4 + r;
                        o[(size_t)gm * CC + ocol] = (_Float16)(acc[i][j][r] + bs);
                    }
                } else {
                    int gm0 = m0 + wm + i * 16 + quad * 4;
                    int b_ = gm0 >> 10, n_ = gm0 & 1023;
                    half4 pk;
                    #pragma unroll
                    for (int r = 0; r < 4; r++) pk[r] = (_Float16)(acc[i][j][r] + bs);
                    size_t idx = ((size_t)(b_ * HH + ho) * 64 + d) * NNN + n_;
                    *(half4*)&((_Float16*)out2)[idx] = pk;
                }
            }
        }
    } else {
        #pragma unroll
        for (int i = 0; i < 4; i++) {
            #pragma unroll
            for (int j = 0; j < 4; j++) {
                int gn = n0 + wn + j * 16 + L;
                float bs = bias0[gn];
                #pragma unroll
                for (int r = 0; r < 4; r++) {
                    int gm = m0 + wm + i * 16 + quad * 4 + r;
                    float v = acc[i][j][r] + bs;
                    size_t idx = (size_t)gm * N + gn;
                    if (MODE == 1) {
                        float vv = 0.5f * v * (1.0f + erff(v * 0.70710678118f));
                        if (gate && !(gate[gn] > 0.0f)) vv = 0.0f;
                        ((_Float16*)out0)[idx] = (_Float16)vv;
                    } else {
                        ((float*)out0)[idx] = res[idx] + v;
                    }
                }
            }
        }
    }
}

// ---------------- MFMA flash attention (active heads only) ----------------
__global__ __launch_bounds__(256) void attn_kernel(
    const _Float16* __restrict__ Q,    // [b][n][h*64+d]
    const _Float16* __restrict__ Kp,   // [b][n][h*64+d]
    const _Float16* __restrict__ Vt,   // [(b*H+h)*64+d][n]
    const int* __restrict__ hmeta,
    const int* __restrict__ hperm,
    _Float16* __restrict__ Y)          // [b][n][h*64+d]
{
    int qt = blockIdx.x;
    int hc = blockIdx.y;
    int b  = blockIdx.z;
    if (hc >= hmeta[1]) return;        // only active heads do work
    int h = hperm[hc];
    int t = threadIdx.x;
    int q0 = qt * 64;
    size_t ybase = ((size_t)b * NNN + q0) * CC + h * DD;

    __shared__ _Float16 Qs[64][72];
    __shared__ _Float16 Ks[64][72];
    __shared__ _Float16 Vs[64][72];   // Vs[d][key]
    __shared__ _Float16 Ps[64][72];

    int lane = t & 63, w = t >> 6;
    int L = lane & 15, quad = lane >> 4;

    {   // stage Q tile, pre-scaled by D^-0.5 = 0.125 (exact in fp16)
        int r = t >> 2, c = (t & 3) * 16;
        const half8* src = (const half8*)(Q + ((size_t)b * NNN + q0 + r) * CC + h * DD + c);
        half8 h0 = src[0], h1 = src[1];
        #pragma unroll
        for (int e = 0; e < 8; e++) { h0[e] = h0[e] * (_Float16)0.125f; h1[e] = h1[e] * (_Float16)0.125f; }
        *(half8*)&Qs[r][c]     = h0;
        *(half8*)&Qs[r][c + 8] = h1;
    }

    floatx4 O[4];
    float m_[4], l_[4];
    #pragma unroll
    for (int i = 0; i < 4; i++) { O[i] = (floatx4){0.f,0.f,0.f,0.f}; m_[i] = -1e30f; l_[i] = 0.0f; }

    const size_t kbase = (size_t)b * NNN * CC + h * DD;
    const size_t vbase = (size_t)(b * HH + h) * DD * NNN;

    for (int kt = 0; kt < 16; ++kt) {
        int k0 = kt * 64;
        __syncthreads();
        {
            int r = t >> 2, c = (t & 3) * 16;
            const half8* ks = (const half8*)(Kp + kbase + (size_t)(k0 + r) * CC + c);
            half8 ka = ks[0], kb = ks[1];
            *(half8*)&Ks[r][c]     = ka;
            *(half8*)&Ks[r][c + 8] = kb;
            const half8* vs = (const half8*)(Vt + vbase + (size_t)r * NNN + k0 + c);
            half8 va = vs[0], vb = vs[1];
            *(half8*)&Vs[r][c]     = va;
            *(half8*)&Vs[r][c + 8] = vb;
        }
        __syncthreads();

        half8 aq0 = *(const half8*)&Qs[16 * w + L][quad * 8];
        half8 aq1 = *(const half8*)&Qs[16 * w + L][quad * 8 + 32];
        floatx4 s[4];
        #pragma unroll
        for (int j = 0; j < 4; j++) {
            half8 b0 = *(const half8*)&Ks[16 * j + L][quad * 8];
            half8 b1 = *(const half8*)&Ks[16 * j + L][quad * 8 + 32];
            floatx4 z = (floatx4){0.f,0.f,0.f,0.f};
            z = __builtin_amdgcn_mfma_f32_16x16x32_f16(aq0, b0, z, 0, 0, 0);
            z = __builtin_amdgcn_mfma_f32_16x16x32_f16(aq1, b1, z, 0, 0, 0);
            s[j] = z;
        }

        #pragma unroll
        for (int r = 0; r < 4; r++) {
            float mx = fmaxf(fmaxf(s[0][r], s[1][r]), fmaxf(s[2][r], s[3][r]));
            mx = fmaxf(mx, __shfl_xor(mx, 1, 64));
            mx = fmaxf(mx, __shfl_xor(mx, 2, 64));
            mx = fmaxf(mx, __shfl_xor(mx, 4, 64));
            mx = fmaxf(mx, __shfl_xor(mx, 8, 64));
            float mnew = fmaxf(m_[r], mx);
            float alpha = __expf(m_[r] - mnew);
            m_[r] = mnew;
            float ps = 0.0f;
            #pragma unroll
            for (int j = 0; j < 4; j++) {
                float p = __expf(s[j][r] - mnew);
                s[j][r] = p; ps += p;
                Ps[16 * w + quad * 4 + r][L + 16 * j] = (_Float16)p;
            }
            ps += __shfl_xor(ps, 1, 64);
            ps += __shfl_xor(ps, 2, 64);
            ps += __shfl_xor(ps, 4, 64);
            ps += __shfl_xor(ps, 8, 64);
            l_[r] = l_[r] * alpha + ps;
            #pragma unroll
            for (int t4 = 0; t4 < 4; t4++) O[t4][r] *= alpha;
        }
        __syncthreads();

        half8 ap0 = *(const half8*)&Ps[16 * w + L][quad * 8];
        half8 ap1 = *(const half8*)&Ps[16 * w + L][quad * 8 + 32];
        #pragma unroll
        for (int t4 = 0; t4 < 4; t4++) {
            half8 b0 = *(const half8*)&Vs[16 * t4 + L][quad * 8];
            half8 b1 = *(const half8*)&Vs[16 * t4 + L][quad * 8 + 32];
            O[t4] = __builtin_amdgcn_mfma_f32_16x16x32_f16(ap0, b0, O[t4], 0, 0, 0);
            O[t4] = __builtin_amdgcn_mfma_f32_16x16x32_f16(ap1, b1, O[t4], 0, 0, 0);
        }
    }

    __syncthreads();
    #pragma unroll
    for (int r = 0; r < 4; r++) {
        float inv = 1.0f / l_[r];
        #pragma unroll
        for (int t4 = 0; t4 < 4; t4++)
            Ps[16 * w + quad * 4 + r][16 * t4 + L] = (_Float16)(O[t4][r] * inv);
    }
    __syncthreads();
    {
        int r = t >> 2, c = (t & 3) * 16;
        half8 o0 = *(const half8*)&Ps[r][c];
        half8 o1 = *(const half8*)&Ps[r][c + 8];
        *(half8*)&Y[ybase + (size_t)r * CC + c]     = o0;
        *(half8*)&Y[ybase + (size_t)r * CC + c + 8] = o1;
    }
}

// ---------------- launch ----------------
extern "C" void kernel_launch(void* const* d_in, const int* in_sizes, int n_in,
                              void* d_out, int out_size, void* d_ws, size_t ws_size,
                              hipStream_t stream)
{
    const float* x      = (const float*)d_in[0];
    const float* ln1_g  = (const float*)d_in[1];
    const float* ln1_b  = (const float*)d_in[2];
    const float* wq     = (const float*)d_in[3];
    const float* bq     = (const float*)d_in[4];
    const float* wk     = (const float*)d_in[5];
    const float* bk     = (const float*)d_in[6];
    const float* wv     = (const float*)d_in[7];
    const float* bv     = (const float*)d_in[8];
    const float* wp     = (const float*)d_in[9];
    const float* bp     = (const float*)d_in[10];
    const float* ln2_g  = (const float*)d_in[11];
    const float* ln2_b  = (const float*)d_in[12];
    const float* w1     = (const float*)d_in[13];
    const float* b1     = (const float*)d_in[14];
    const float* w2     = (const float*)d_in[15];
    const float* b2     = (const float*)d_in[16];
    const float* gate_h = (const float*)d_in[17];
    const float* gate_f = (const float*)d_in[18];

    char* ws = (char*)d_ws;
    _Float16* WQKVc = (_Float16*)(ws + 0);        // compacted [3*Hpad*64][768] fp16
    _Float16* WPh = (_Float16*)(ws + 3538944);
    _Float16* W1c = (_Float16*)(ws + 4718592);    // compacted rows of w1
    _Float16* W2c = (_Float16*)(ws + 9437184);    // compacted cols of w2
    _Float16* XN  = (_Float16*)(ws + 14155776);
    _Float16* Qb  = (_Float16*)(ws + 39321600);
    _Float16* Kb  = (_Float16*)(ws + 64487424);
    _Float16* Vtb = (_Float16*)(ws + 89653248);   // V transposed: [(b*H+h)*64+d][n]
    _Float16* Yb  = (_Float16*)(ws + 114819072);
    float*    X1  = (float*)   (ws + 139984896);
    _Float16* XN2 = (_Float16*)(ws + 114819072);  // aliases Yb (dead after proj)
    _Float16* F1  = (_Float16*)(ws + 14155776);   // aliases XN/Q/K/Vt (dead by then)
    int*      meta = (int*)    (ws + 190316544);  // [0]=Na_pad128 [1]=Na
    int*      perm = (int*)    (ws + 190316800);  // 3072 ints
    float*    b1c  = (float*)  (ws + 190329088);  // 3072 floats
    int*      hmeta = (int*)   (ws + 190341376);  // [0]=3*Hpad*64 [1]=Ha [2]=Hpad*64
    int*      hperm = (int*)   (ws + 190341440);  // 12 ints

    // compactions
    scan_kernel<<<1, 256, 0, stream>>>(gate_f, b1, meta, perm, b1c);
    scanh_kernel<<<1, 64, 0, stream>>>(gate_h, hmeta, hperm);

    // weight converts / gathers
    gatherQKV_kernel<<<1728, 256, 0, stream>>>(wq, wk, wv, hmeta, hperm, WQKVc);
    cvt_kernel<<<576, 256, 0, stream>>>(wp, WPh, 147456);
    gatherW1_kernel<<<2304, 256, 0, stream>>>(w1, perm, W1c);
    gatherW2_kernel<<<2304, 256, 0, stream>>>(w2, perm, W2c);

    // LN1
    ln_kernel<<<ROWS, 256, 0, stream>>>(x, ln1_g, ln1_b, XN);

    // compacted QKV projection: GM=128 x GN=18 (blocks beyond 3*Hpad*64 exit)
    gemm_kernel<0><<<2304, 256, 0, stream>>>(
        XN, WQKVc, bq, bk, bv, nullptr, nullptr, nullptr, Qb, Kb, Vtb, hmeta, hperm, ROWS, 2304, CC);

    // attention (active heads only; masked heads' Y never read by proj)
    attn_kernel<<<dim3(16, HH, BB), 256, 0, stream>>>(Qb, Kb, Vtb, hmeta, hperm, Yb);

    // proj + residual -> X1 (fp32); masked-head K-blocks skipped via kmask
    gemm_kernel<2><<<768, 256, 0, stream>>>(
        Yb, WPh, bp, nullptr, nullptr, x, nullptr, gate_h, X1, nullptr, nullptr, nullptr, nullptr, ROWS, CC, CC);

    // LN2
    ln_kernel<<<ROWS, 256, 0, stream>>>(X1, ln2_g, ln2_b, XN2);

    // MLP1 (compacted width Na_pad; half the n-blocks exit) -> F1 fp16
    gemm_kernel<1><<<3072, 256, 0, stream>>>(
        XN2, W1c, b1c, nullptr, nullptr, nullptr, nullptr, nullptr, F1, nullptr, nullptr, meta, nullptr, ROWS, HIDN, CC);

    // MLP2 + residual -> out fp32 (K sweep bounded by meta[0])
    gemm_kernel<2><<<768, 256, 0, stream>>>(
        F1, W2c, b2, nullptr, nullptr, X1, nullptr, nullptr, (float*)d_out, nullptr, nullptr, meta, nullptr, ROWS, CC, HIDN);
}

// Round 8
// 470.839 us; speedup vs baseline: 1.4810x; 1.4810x over previous
//
#include <hip/hip_runtime.h>

#define BB 16
#define NNN 1024
#define CC 768
#define HH 12
#define DD 64
#define HIDN 3072
#define ROWS (BB*NNN)   // 16384

typedef _Float16 half8 __attribute__((ext_vector_type(8)));
typedef _Float16 half4 __attribute__((ext_vector_type(4)));
typedef float floatx4 __attribute__((ext_vector_type(4)));

#define GLOAD_LDS(g, l) __builtin_amdgcn_global_load_lds( \
    (const __attribute__((address_space(1))) void*)(g),    \
    (__attribute__((address_space(3))) void*)(l), 16, 0, 0)

// raw barrier: compiler memory fence but NO s_waitcnt vmcnt(0) drain
#define RAW_BARRIER() do { asm volatile("" ::: "memory"); \
    __builtin_amdgcn_s_barrier(); asm volatile("" ::: "memory"); } while (0)
// wait until <= n vector-memory ops outstanding (exp/lgkm unmasked); n must be literal
#define VMCNT_WAIT(n) __builtin_amdgcn_s_waitcnt((n) | 0x0F70)

// ---------------- weight fp32 -> fp16 convert ----------------
__global__ void cvt_kernel(const float* __restrict__ src, _Float16* __restrict__ dst, int n4) {
    int i = blockIdx.x * blockDim.x + threadIdx.x;
    if (i < n4) {
        floatx4 v = ((const floatx4*)src)[i];
        half4 h;
        h[0] = (_Float16)v[0]; h[1] = (_Float16)v[1];
        h[2] = (_Float16)v[2]; h[3] = (_Float16)v[3];
        ((half4*)dst)[i] = h;
    }
}

// ---------------- head compaction ----------------
// gate_h>0 <=> active head; ~half are hard-masked.  Order-preserving perm.
// hmeta[0]=3*Hpad*64 (QKV N bound), hmeta[1]=Ha, hmeta[2]=Hpad*64 (seg width),
// Hpad = Ha rounded up to even (so segment width is a multiple of 128).
__global__ void scanh_kernel(const float* __restrict__ gh, int* __restrict__ hmeta,
                             int* __restrict__ hperm) {
    if (threadIdx.x == 0 && blockIdx.x == 0) {
        int c = 0;
        for (int i = 0; i < HH; i++) if (gh[i] > 0.0f) hperm[c++] = i;
        for (int i = c; i < HH; i++) hperm[i] = -1;
        int Hp = (c + 1) & ~1;
        hmeta[1] = c;
        hmeta[2] = Hp * 64;
        hmeta[0] = 3 * Hp * 64;
    }
}

// wq|wk|wv [768][768] f32 -> compacted fp16 [3*Hpad*64][768] (active heads only)
__global__ void gatherQKV_kernel(const float* __restrict__ wq, const float* __restrict__ wk,
                                 const float* __restrict__ wv, const int* __restrict__ hmeta,
                                 const int* __restrict__ hperm, _Float16* __restrict__ dst) {
    int i = blockIdx.x * blockDim.x + threadIdx.x;   // over 2304*192 float4 chunks
    int row = i / 192, c4 = i - row * 192;
    if (row >= hmeta[0]) return;
    int segw = hmeta[2];
    int seg = row / segw, rem = row - seg * segw;
    int ho = hperm[rem >> 6];
    half4 h; h[0] = h[1] = h[2] = h[3] = (_Float16)0.0f;
    if (ho >= 0) {
        const float* src = (seg == 0 ? wq : seg == 1 ? wk : wv) +
                           (size_t)(ho * 64 + (rem & 63)) * CC;
        floatx4 v = ((const floatx4*)src)[c4];
        h[0] = (_Float16)v[0]; h[1] = (_Float16)v[1];
        h[2] = (_Float16)v[2]; h[3] = (_Float16)v[3];
    }
    ((half4*)&dst[(size_t)row * CC])[c4] = h;
}

// ---------------- FFN channel compaction ----------------
// gate_f masks ~half the FFN channels to EXACT zero in F1.  Order-preserving
// perm of active channels + compacted bias.  meta[0]=Na_pad128, meta[1]=Na.
__global__ __launch_bounds__(256) void scan_kernel(const float* __restrict__ gf,
                                                   const float* __restrict__ b1,
                                                   int* __restrict__ meta,
                                                   int* __restrict__ perm,
                                                   float* __restrict__ b1c) {
    int t = threadIdx.x;            // 256 threads x 12 elems = 3072
    int base = t * 12;
    bool act[12];
    int cnt = 0;
    #pragma unroll
    for (int i = 0; i < 12; i++) { bool a = gf[base + i] > 0.0f; act[i] = a; cnt += a ? 1 : 0; }
    __shared__ int cs[256];
    cs[t] = cnt;
    __syncthreads();
    if (t == 0) {
        int s = 0;
        for (int i = 0; i < 256; i++) { int c = cs[i]; cs[i] = s; s += c; }
        meta[1] = s;
        meta[0] = (s + 127) & ~127;
    }
    __syncthreads();
    int off = cs[t];
    for (int i = t; i < HIDN; i += 256) { b1c[i] = 0.0f; perm[i] = -1; }
    __syncthreads();
    #pragma unroll
    for (int i = 0; i < 12; i++)
        if (act[i]) { perm[off] = base + i; b1c[off] = b1[base + i]; off++; }
}

// W1 [3072][768] f32 -> W1c: compacted rows (perm), fp16, zero pad rows
__global__ void gatherW1_kernel(const float* __restrict__ src, const int* __restrict__ perm,
                                _Float16* __restrict__ dst) {
    int i = blockIdx.x * blockDim.x + threadIdx.x;   // over 3072*192 float4 chunks
    int row = i / 192, c4 = i - row * 192;
    int s = perm[row];
    half4 h; h[0] = h[1] = h[2] = h[3] = (_Float16)0.0f;
    if (s >= 0) {
        floatx4 v = ((const floatx4*)(src + (size_t)s * CC))[c4];
        h[0] = (_Float16)v[0]; h[1] = (_Float16)v[1];
        h[2] = (_Float16)v[2]; h[3] = (_Float16)v[3];
    }
    ((half4*)dst)[i] = h;
}

// W2 [768][3072] f32 -> W2c: compacted COLUMNS (perm), fp16, zero pad cols
__global__ void gatherW2_kernel(const float* __restrict__ src, const int* __restrict__ perm,
                                _Float16* __restrict__ dst) {
    int i = blockIdx.x * blockDim.x + threadIdx.x;   // over 768*768 groups of 4 cols
    int n = i / 768, j4 = (i - n * 768) * 4;
    const float* r = src + (size_t)n * HIDN;
    half4 h;
    #pragma unroll
    for (int e = 0; e < 4; e++) {
        int s = perm[j4 + e];
        h[e] = (s >= 0) ? (_Float16)r[s] : (_Float16)0.0f;
    }
    *(half4*)&dst[(size_t)n * HIDN + j4] = h;
}

// ---------------- LayerNorm (row of 768), fp32 in -> fp16 out ----------------
__global__ __launch_bounds__(256) void ln_kernel(const float* __restrict__ x,
                                                 const float* __restrict__ g,
                                                 const float* __restrict__ b,
                                                 _Float16* __restrict__ out) {
    int row = blockIdx.x;
    int t = threadIdx.x;
    const float* xr = x + (size_t)row * CC;
    float v0 = xr[t], v1 = xr[t + 256], v2 = xr[t + 512];
    float s = v0 + v1 + v2;
    float q = v0 * v0 + v1 * v1 + v2 * v2;
    #pragma unroll
    for (int m = 1; m < 64; m <<= 1) {
        s += __shfl_xor(s, m, 64);
        q += __shfl_xor(q, m, 64);
    }
    __shared__ float red[8];
    int wv = t >> 6, lane = t & 63;
    if (lane == 0) { red[wv] = s; red[wv + 4] = q; }
    __syncthreads();
    s = red[0] + red[1] + red[2] + red[3];
    q = red[4] + red[5] + red[6] + red[7];
    float mean = s * (1.0f / CC);
    float var = q * (1.0f / CC) - mean * mean;
    float rs = rsqrtf(var + 1e-5f);
    _Float16* orow = out + (size_t)row * CC;
    orow[t]       = (_Float16)((v0 - mean) * rs * g[t]       + b[t]);
    orow[t + 256] = (_Float16)((v1 - mean) * rs * g[t + 256] + b[t + 256]);
    orow[t + 512] = (_Float16)((v2 - mean) * rs * g[t + 512] + b[t + 512]);
}

// ---------------- MFMA GEMM: r5 LDS structure + head compaction -------------
// r6 post-mortem: all-register (global-direct fragments) = 2.2x WORSE (L1 path
// slower than LDS + 2x duplication).  r5's LDS double-buffered TM=128/BK=32 is
// the best measured structure (~1570 cy per 128x128x32 k-unit/CU).  Wins come
// from FLOP elimination: FFN compaction (proven) + HEAD compaction (this rev).
// LDS swizzle: phys 16B-chunk p of row r holds k-chunk p^((r>>2)&3);
// pre-swizzled GLOBAL src, linear gload_lds dest; read at chunk quad^((L>>2)&3).
// MODE 0: compacted QKV (meta=hmeta; epilogue scatters to original head slots)
// MODE 1: out fp16 = gelu(acc + bias0); meta[0] = compacted-FFN N bound
// MODE 2: out fp32 = res + acc + bias0; kmask (hgate) skips masked-head K; meta[0]=eff.K
template <int MODE>
__global__ __launch_bounds__(256) void gemm_kernel(
    const _Float16* __restrict__ A,
    const _Float16* __restrict__ W,
    const float* __restrict__ bias0,
    const float* __restrict__ bias1,
    const float* __restrict__ bias2,
    const float* __restrict__ res,
    const float* __restrict__ gate,
    const float* __restrict__ hgate,
    void* __restrict__ out0,
    void* __restrict__ out1,
    void* __restrict__ out2,
    const int* __restrict__ meta,
    const int* __restrict__ hperm,
    int M, int N, int K)
{
    // XCD-aware swizzle (GM=128 -> 16 m-stripes per XCD)
    int GN = N >> 7, GM = M >> 7;
    int f = blockIdx.x;
    int xcd = f & 7, slot = f >> 3;
    int m_idx = xcd * (GM >> 3) + slot / GN;
    int n_idx = slot - (slot / GN) * GN;
    int m0 = m_idx * 128, n0 = n_idx * 128;

    int Klen = K;
    if (MODE == 0 || MODE == 1) { if (n0 >= meta[0]) return; }  // compacted width
    if (MODE == 2 && meta) Klen = meta[0];                      // compacted K sweep

    // K-block gate mask (proj: zero A-columns from masked heads), 64-k granularity
    unsigned kmask = 0xFFFFFFFFu;
    if (MODE == 2 && hgate) {
        kmask = 0;
        for (int i = 0; i < HH; i++) kmask |= (hgate[i] > 0.0f ? 1u : 0u) << i;
    }

    __shared__ _Float16 As[2][128 * 32];   // 16KB, row stride 32 halfs (64B)
    __shared__ _Float16 Bs[2][128 * 32];   // 16KB
    int t = threadIdx.x;
    int lane = t & 63, w = t >> 6;
    int wm = (w >> 1) * 64, wn = (w & 1) * 64;
    int L = lane & 15, quad = lane >> 4;
    int rchunk = (quad ^ ((L >> 2) & 3)) * 8;   // swizzled k-chunk for fragment reads

    floatx4 acc[4][4];
    #pragma unroll
    for (int i = 0; i < 4; i++)
        #pragma unroll
        for (int j = 0; j < 4; j++)
            acc[i][j] = (floatx4){0.f, 0.f, 0.f, 0.f};

    // staging: physical chunk pc = issue*256 + t; row = pc>>2, kc = (pc&3)^((pc>>4)&3)
    const _Float16* agp[2];
    const _Float16* bgp[2];
    #pragma unroll
    for (int i = 0; i < 2; i++) {
        int pc = i * 256 + t;
        int row = pc >> 2;
        int kc = (pc & 3) ^ ((pc >> 4) & 3);
        agp[i] = A + (size_t)(m0 + row) * K + kc * 8;
        bgp[i] = W + (size_t)(n0 + row) * K + kc * 8;
    }
    unsigned wb = (unsigned)w * 512;   // wave-uniform LDS base (halfs) per issue block

    auto nextk = [&](int k0) -> int {
        if (MODE == 2)
            while (k0 < Klen && !((kmask >> ((k0 >> 6) & 31)) & 1)) k0 += 32;
        return k0;
    };
    auto stage = [&](int buf, int k0) {
        #pragma unroll
        for (int i = 0; i < 2; i++) GLOAD_LDS(agp[i] + k0, &As[buf][i * 2048 + wb]);
        #pragma unroll
        for (int i = 0; i < 2; i++) GLOAD_LDS(bgp[i] + k0, &Bs[buf][i * 2048 + wb]);
    };
    auto compute = [&](int buf) {
        half8 af[4], bf[4];
        #pragma unroll
        for (int i = 0; i < 4; i++) af[i] = *(const half8*)&As[buf][(wm + i * 16 + L) * 32 + rchunk];
        #pragma unroll
        for (int j = 0; j < 4; j++)  bf[j] = *(const half8*)&Bs[buf][(wn + j * 16 + L) * 32 + rchunk];
        #pragma unroll
        for (int i = 0; i < 4; i++)
            #pragma unroll
            for (int j = 0; j < 4; j++)
                acc[i][j] = __builtin_amdgcn_mfma_f32_16x16x32_f16(af[i], bf[j], acc[i][j], 0, 0, 0);
    };

    int kcur = nextk(0);
    if (kcur < Klen) {
        stage(0, kcur);
        int kn1 = nextk(kcur + 32);
        int kn2 = Klen;
        if (kn1 < Klen) { stage(1, kn1); kn2 = nextk(kn1 + 32); }
        int buf = 0;
        while (kn2 < Klen) {            // steady state: next tile in flight
            VMCNT_WAIT(4);              // current tile landed (4 issues/tile)
            RAW_BARRIER();
            compute(buf);
            RAW_BARRIER();              // all waves done reading buf before restage
            stage(buf, kn2);
            buf ^= 1;
            kn1 = kn2; kn2 = nextk(kn2 + 32);
        }
        if (kn1 < Klen) {               // two tiles left, both staged
            VMCNT_WAIT(4);
            RAW_BARRIER();
            compute(buf);
            buf ^= 1;
        }
        VMCNT_WAIT(0);                  // last tile
        RAW_BARRIER();
        compute(buf);
    }

    // epilogue: C row = quad*4 + r (M side), col = L (N side)  [verified m89/m91 layout]
    if (MODE == 0) {
        int segw = meta[2];
        int seg = n0 / segw;
        int cbase = n0 - seg * segw + wn;   // head-col base within segment (mult of 64)
        int ho = hperm[cbase >> 6];         // original head (uniform per wave)
        if (ho < 0) return;                 // pad head: outputs never read
        #pragma unroll
        for (int i = 0; i < 4; i++) {
            #pragma unroll
            for (int j = 0; j < 4; j++) {
                int d = j * 16 + L;         // 0..63 within head
                int ocol = ho * 64 + d;
                const float* bsel = (seg == 0) ? bias0 : (seg == 1) ? bias1 : bias2;
                float bs = bsel[ocol];
                if (seg < 2) {
                    _Float16* o = (_Float16*)((seg == 0) ? out0 : out1);
                    #pragma unroll
                    for (int r = 0; r < 4; r++) {
                        int gm = m0 + wm + i * 16 + quad * 4 + r;
                        o[(size_t)gm * CC + ocol] = (_Float16)(acc[i][j][r] + bs);
                    }
                } else {
                    int gm0 = m0 + wm + i * 16 + quad * 4;
                    int b_ = gm0 >> 10, n_ = gm0 & 1023;
                    half4 pk;
                    #pragma unroll
                    for (int r = 0; r < 4; r++) pk[r] = (_Float16)(acc[i][j][r] + bs);
                    size_t idx = ((size_t)(b_ * HH + ho) * 64 + d) * NNN + n_;
                    *(half4*)&((_Float16*)out2)[idx] = pk;
                }
            }
        }
    } else {
        #pragma unroll
        for (int i = 0; i < 4; i++) {
            #pragma unroll
            for (int j = 0; j < 4; j++) {
                int gn = n0 + wn + j * 16 + L;
                float bs = bias0[gn];
                #pragma unroll
                for (int r = 0; r < 4; r++) {
                    int gm = m0 + wm + i * 16 + quad * 4 + r;
                    float v = acc[i][j][r] + bs;
                    size_t idx = (size_t)gm * N + gn;
                    if (MODE == 1) {
                        float vv = 0.5f * v * (1.0f + erff(v * 0.70710678118f));
                        if (gate && !(gate[gn] > 0.0f)) vv = 0.0f;
                        ((_Float16*)out0)[idx] = (_Float16)vv;
                    } else {
                        ((float*)out0)[idx] = res[idx] + v;
                    }
                }
            }
        }
    }
}

// ---------------- MFMA flash attention (active heads only) ----------------
__global__ __launch_bounds__(256) void attn_kernel(
    const _Float16* __restrict__ Q,    // [b][n][h*64+d]
    const _Float16* __restrict__ Kp,   // [b][n][h*64+d]
    const _Float16* __restrict__ Vt,   // [(b*H+h)*64+d][n]
    const int* __restrict__ hmeta,
    const int* __restrict__ hperm,
    _Float16* __restrict__ Y)          // [b][n][h*64+d]
{
    int qt = blockIdx.x;
    int hc = blockIdx.y;
    int b  = blockIdx.z;
    if (hc >= hmeta[1]) return;        // only active heads do work
    int h = hperm[hc];
    int t = threadIdx.x;
    int q0 = qt * 64;
    size_t ybase = ((size_t)b * NNN + q0) * CC + h * DD;

    __shared__ _Float16 Qs[64][72];
    __shared__ _Float16 Ks[64][72];
    __shared__ _Float16 Vs[64][72];   // Vs[d][key]
    __shared__ _Float16 Ps[64][72];

    int lane = t & 63, w = t >> 6;
    int L = lane & 15, quad = lane >> 4;

    {   // stage Q tile, pre-scaled by D^-0.5 = 0.125 (exact in fp16)
        int r = t >> 2, c = (t & 3) * 16;
        const half8* src = (const half8*)(Q + ((size_t)b * NNN + q0 + r) * CC + h * DD + c);
        half8 h0 = src[0], h1 = src[1];
        #pragma unroll
        for (int e = 0; e < 8; e++) { h0[e] = h0[e] * (_Float16)0.125f; h1[e] = h1[e] * (_Float16)0.125f; }
        *(half8*)&Qs[r][c]     = h0;
        *(half8*)&Qs[r][c + 8] = h1;
    }

    floatx4 O[4];
    float m_[4], l_[4];
    #pragma unroll
    for (int i = 0; i < 4; i++) { O[i] = (floatx4){0.f,0.f,0.f,0.f}; m_[i] = -1e30f; l_[i] = 0.0f; }

    const size_t kbase = (size_t)b * NNN * CC + h * DD;
    const size_t vbase = (size_t)(b * HH + h) * DD * NNN;

    for (int kt = 0; kt < 16; ++kt) {
        int k0 = kt * 64;
        __syncthreads();
        {
            int r = t >> 2, c = (t & 3) * 16;
            const half8* ks = (const half8*)(Kp + kbase + (size_t)(k0 + r) * CC + c);
            half8 ka = ks[0], kb = ks[1];
            *(half8*)&Ks[r][c]     = ka;
            *(half8*)&Ks[r][c + 8] = kb;
            const half8* vs = (const half8*)(Vt + vbase + (size_t)r * NNN + k0 + c);
            half8 va = vs[0], vb = vs[1];
            *(half8*)&Vs[r][c]     = va;
            *(half8*)&Vs[r][c + 8] = vb;
        }
        __syncthreads();

        half8 aq0 = *(const half8*)&Qs[16 * w + L][quad * 8];
        half8 aq1 = *(const half8*)&Qs[16 * w + L][quad * 8 + 32];
        floatx4 s[4];
        #pragma unroll
        for (int j = 0; j < 4; j++) {
            half8 b0 = *(const half8*)&Ks[16 * j + L][quad * 8];
            half8 b1 = *(const half8*)&Ks[16 * j + L][quad * 8 + 32];
            floatx4 z = (floatx4){0.f,0.f,0.f,0.f};
            z = __builtin_amdgcn_mfma_f32_16x16x32_f16(aq0, b0, z, 0, 0, 0);
            z = __builtin_amdgcn_mfma_f32_16x16x32_f16(aq1, b1, z, 0, 0, 0);
            s[j] = z;
        }

        #pragma unroll
        for (int r = 0; r < 4; r++) {
            float mx = fmaxf(fmaxf(s[0][r], s[1][r]), fmaxf(s[2][r], s[3][r]));
            mx = fmaxf(mx, __shfl_xor(mx, 1, 64));
            mx = fmaxf(mx, __shfl_xor(mx, 2, 64));
            mx = fmaxf(mx, __shfl_xor(mx, 4, 64));
            mx = fmaxf(mx, __shfl_xor(mx, 8, 64));
            float mnew = fmaxf(m_[r], mx);
            float alpha = __expf(m_[r] - mnew);
            m_[r] = mnew;
            float ps = 0.0f;
            #pragma unroll
            for (int j = 0; j < 4; j++) {
                float p = __expf(s[j][r] - mnew);
                s[j][r] = p; ps += p;
                Ps[16 * w + quad * 4 + r][L + 16 * j] = (_Float16)p;
            }
            ps += __shfl_xor(ps, 1, 64);
            ps += __shfl_xor(ps, 2, 64);
            ps += __shfl_xor(ps, 4, 64);
            ps += __shfl_xor(ps, 8, 64);
            l_[r] = l_[r] * alpha + ps;
            #pragma unroll
            for (int t4 = 0; t4 < 4; t4++) O[t4][r] *= alpha;
        }
        __syncthreads();

        half8 ap0 = *(const half8*)&Ps[16 * w + L][quad * 8];
        half8 ap1 = *(const half8*)&Ps[16 * w + L][quad * 8 + 32];
        #pragma unroll
        for (int t4 = 0; t4 < 4; t4++) {
            half8 b0 = *(const half8*)&Vs[16 * t4 + L][quad * 8];
            half8 b1 = *(const half8*)&Vs[16 * t4 + L][quad * 8 + 32];
            O[t4] = __builtin_amdgcn_mfma_f32_16x16x32_f16(ap0, b0, O[t4], 0, 0, 0);
            O[t4] = __builtin_amdgcn_mfma_f32_16x16x32_f16(ap1, b1, O[t4], 0, 0, 0);
        }
    }

    __syncthreads();
    #pragma unroll
    for (int r = 0; r < 4; r++) {
        float inv = 1.0f / l_[r];
        #pragma unroll
        for (int t4 = 0; t4 < 4; t4++)
            Ps[16 * w + quad * 4 + r][16 * t4 + L] = (_Float16)(O[t4][r] * inv);
    }
    __syncthreads();
    {
        int r = t >> 2, c = (t & 3) * 16;
        half8 o0 = *(const half8*)&Ps[r][c];
        half8 o1 = *(const half8*)&Ps[r][c + 8];
        *(half8*)&Y[ybase + (size_t)r * CC + c]     = o0;
        *(half8*)&Y[ybase + (size_t)r * CC + c + 8] = o1;
    }
}

// ---------------- launch ----------------
extern "C" void kernel_launch(void* const* d_in, const int* in_sizes, int n_in,
                              void* d_out, int out_size, void* d_ws, size_t ws_size,
                              hipStream_t stream)
{
    const float* x      = (const float*)d_in[0];
    const float* ln1_g  = (const float*)d_in[1];
    const float* ln1_b  = (const float*)d_in[2];
    const float* wq     = (const float*)d_in[3];
    const float* bq     = (const float*)d_in[4];
    const float* wk     = (const float*)d_in[5];
    const float* bk     = (const float*)d_in[6];
    const float* wv     = (const float*)d_in[7];
    const float* bv     = (const float*)d_in[8];
    const float* wp     = (const float*)d_in[9];
    const float* bp     = (const float*)d_in[10];
    const float* ln2_g  = (const float*)d_in[11];
    const float* ln2_b  = (const float*)d_in[12];
    const float* w1     = (const float*)d_in[13];
    const float* b1     = (const float*)d_in[14];
    const float* w2     = (const float*)d_in[15];
    const float* b2     = (const float*)d_in[16];
    const float* gate_h = (const float*)d_in[17];
    const float* gate_f = (const float*)d_in[18];

    char* ws = (char*)d_ws;
    _Float16* WQKVc = (_Float16*)(ws + 0);        // compacted [3*Hpad*64][768] fp16
    _Float16* WPh = (_Float16*)(ws + 3538944);
    _Float16* W1c = (_Float16*)(ws + 4718592);    // compacted rows of w1
    _Float16* W2c = (_Float16*)(ws + 9437184);    // compacted cols of w2
    _Float16* XN  = (_Float16*)(ws + 14155776);
    _Float16* Qb  = (_Float16*)(ws + 39321600);
    _Float16* Kb  = (_Float16*)(ws + 64487424);
    _Float16* Vtb = (_Float16*)(ws + 89653248);   // V transposed: [(b*H+h)*64+d][n]
    _Float16* Yb  = (_Float16*)(ws + 114819072);
    float*    X1  = (float*)   (ws + 139984896);
    _Float16* XN2 = (_Float16*)(ws + 114819072);  // aliases Yb (dead after proj)
    _Float16* F1  = (_Float16*)(ws + 14155776);   // aliases XN/Q/K/Vt (dead by then)
    int*      meta = (int*)    (ws + 190316544);  // [0]=Na_pad128 [1]=Na
    int*      perm = (int*)    (ws + 190316800);  // 3072 ints
    float*    b1c  = (float*)  (ws + 190329088);  // 3072 floats
    int*      hmeta = (int*)   (ws + 190341376);  // [0]=3*Hpad*64 [1]=Ha [2]=Hpad*64
    int*      hperm = (int*)   (ws + 190341440);  // 12 ints

    // compactions
    scan_kernel<<<1, 256, 0, stream>>>(gate_f, b1, meta, perm, b1c);
    scanh_kernel<<<1, 64, 0, stream>>>(gate_h, hmeta, hperm);

    // weight converts / gathers
    gatherQKV_kernel<<<1728, 256, 0, stream>>>(wq, wk, wv, hmeta, hperm, WQKVc);
    cvt_kernel<<<576, 256, 0, stream>>>(wp, WPh, 147456);
    gatherW1_kernel<<<2304, 256, 0, stream>>>(w1, perm, W1c);
    gatherW2_kernel<<<2304, 256, 0, stream>>>(w2, perm, W2c);

    // LN1
    ln_kernel<<<ROWS, 256, 0, stream>>>(x, ln1_g, ln1_b, XN);

    // compacted QKV projection: GM=128 x GN=18 (blocks beyond 3*Hpad*64 exit)
    gemm_kernel<0><<<2304, 256, 0, stream>>>(
        XN, WQKVc, bq, bk, bv, nullptr, nullptr, nullptr, Qb, Kb, Vtb, hmeta, hperm, ROWS, 2304, CC);

    // attention (active heads only; masked heads' Y never read by proj)
    attn_kernel<<<dim3(16, HH, BB), 256, 0, stream>>>(Qb, Kb, Vtb, hmeta, hperm, Yb);

    // proj + residual -> X1 (fp32); masked-head K-blocks skipped via kmask
    gemm_kernel<2><<<768, 256, 0, stream>>>(
        Yb, WPh, bp, nullptr, nullptr, x, nullptr, gate_h, X1, nullptr, nullptr, nullptr, nullptr, ROWS, CC, CC);

    // LN2
    ln_kernel<<<ROWS, 256, 0, stream>>>(X1, ln2_g, ln2_b, XN2);

    // MLP1 (compacted width Na_pad; ~half the n-blocks exit) -> F1 fp16
    gemm_kernel<1><<<3072, 256, 0, stream>>>(
        XN2, W1c, b1c, nullptr, nullptr, nullptr, nullptr, nullptr, F1, nullptr, nullptr, meta, nullptr, ROWS, HIDN, CC);

    // MLP2 + residual -> out fp32 (K sweep bounded by meta[0])
    gemm_kernel<2><<<768, 256, 0, stream>>>(
        F1, W2c, b2, nullptr, nullptr, X1, nullptr, nullptr, (float*)d_out, nullptr, nullptr, meta, nullptr, ROWS, CC, HIDN);
}

// Round 9
// 449.602 us; speedup vs baseline: 1.5509x; 1.0472x over previous
//
#include <hip/hip_runtime.h>

#define BB 16
#define NNN 1024
#define CC 768
#define HH 12
#define DD 64
#define HIDN 3072
#define ROWS (BB*NNN)   // 16384

typedef _Float16 half8 __attribute__((ext_vector_type(8)));
typedef _Float16 half4 __attribute__((ext_vector_type(4)));
typedef float floatx4 __attribute__((ext_vector_type(4)));

#define GLOAD_LDS(g, l) __builtin_amdgcn_global_load_lds( \
    (const __attribute__((address_space(1))) void*)(g),    \
    (__attribute__((address_space(3))) void*)(l), 16, 0, 0)

// raw barrier: compiler memory fence but NO s_waitcnt vmcnt(0) drain
#define RAW_BARRIER() do { asm volatile("" ::: "memory"); \
    __builtin_amdgcn_s_barrier(); asm volatile("" ::: "memory"); } while (0)
// wait until <= n vector-memory ops outstanding (exp/lgkm unmasked); n must be literal
#define VMCNT_WAIT(n) __builtin_amdgcn_s_waitcnt((n) | 0x0F70)

// ---------------- weight fp32 -> fp16 convert ----------------
__global__ void cvt_kernel(const float* __restrict__ src, _Float16* __restrict__ dst, int n4) {
    int i = blockIdx.x * blockDim.x + threadIdx.x;
    if (i < n4) {
        floatx4 v = ((const floatx4*)src)[i];
        half4 h;
        h[0] = (_Float16)v[0]; h[1] = (_Float16)v[1];
        h[2] = (_Float16)v[2]; h[3] = (_Float16)v[3];
        ((half4*)dst)[i] = h;
    }
}

// ---------------- head compaction ----------------
// gate_h>0 <=> active head; ~half are hard-masked.  Order-preserving perm.
// hmeta[0]=3*Hpad*64 (QKV N bound), hmeta[1]=Ha, hmeta[2]=Hpad*64 (seg width),
// Hpad = Ha rounded up to even (so segment width is a multiple of 128).
__global__ void scanh_kernel(const float* __restrict__ gh, int* __restrict__ hmeta,
                             int* __restrict__ hperm) {
    if (threadIdx.x == 0 && blockIdx.x == 0) {
        int c = 0;
        for (int i = 0; i < HH; i++) if (gh[i] > 0.0f) hperm[c++] = i;
        for (int i = c; i < HH; i++) hperm[i] = -1;
        int Hp = (c + 1) & ~1;
        hmeta[1] = c;
        hmeta[2] = Hp * 64;
        hmeta[0] = 3 * Hp * 64;
    }
}

// wq|wk|wv [768][768] f32 -> compacted fp16 [3*Hpad*64][768] (active heads only)
__global__ void gatherQKV_kernel(const float* __restrict__ wq, const float* __restrict__ wk,
                                 const float* __restrict__ wv, const int* __restrict__ hmeta,
                                 const int* __restrict__ hperm, _Float16* __restrict__ dst) {
    int i = blockIdx.x * blockDim.x + threadIdx.x;   // over 2304*192 float4 chunks
    int row = i / 192, c4 = i - row * 192;
    if (row >= hmeta[0]) return;
    int segw = hmeta[2];
    int seg = row / segw, rem = row - seg * segw;
    int ho = hperm[rem >> 6];
    half4 h; h[0] = h[1] = h[2] = h[3] = (_Float16)0.0f;
    if (ho >= 0) {
        const float* src = (seg == 0 ? wq : seg == 1 ? wk : wv) +
                           (size_t)(ho * 64 + (rem & 63)) * CC;
        floatx4 v = ((const floatx4*)src)[c4];
        h[0] = (_Float16)v[0]; h[1] = (_Float16)v[1];
        h[2] = (_Float16)v[2]; h[3] = (_Float16)v[3];
    }
    ((half4*)&dst[(size_t)row * CC])[c4] = h;
}

// ---------------- FFN channel compaction ----------------
// gate_f masks ~half the FFN channels to EXACT zero in F1.  Order-preserving
// perm of active channels + compacted bias.  meta[0]=Na_pad128, meta[1]=Na.
__global__ __launch_bounds__(256) void scan_kernel(const float* __restrict__ gf,
                                                   const float* __restrict__ b1,
                                                   int* __restrict__ meta,
                                                   int* __restrict__ perm,
                                                   float* __restrict__ b1c) {
    int t = threadIdx.x;            // 256 threads x 12 elems = 3072
    int base = t * 12;
    bool act[12];
    int cnt = 0;
    #pragma unroll
    for (int i = 0; i < 12; i++) { bool a = gf[base + i] > 0.0f; act[i] = a; cnt += a ? 1 : 0; }
    __shared__ int cs[256];
    cs[t] = cnt;
    __syncthreads();
    if (t == 0) {
        int s = 0;
        for (int i = 0; i < 256; i++) { int c = cs[i]; cs[i] = s; s += c; }
        meta[1] = s;
        meta[0] = (s + 127) & ~127;
    }
    __syncthreads();
    int off = cs[t];
    for (int i = t; i < HIDN; i += 256) { b1c[i] = 0.0f; perm[i] = -1; }
    __syncthreads();
    #pragma unroll
    for (int i = 0; i < 12; i++)
        if (act[i]) { perm[off] = base + i; b1c[off] = b1[base + i]; off++; }
}

// W1 [3072][768] f32 -> W1c: compacted rows (perm), fp16, zero pad rows
__global__ void gatherW1_kernel(const float* __restrict__ src, const int* __restrict__ perm,
                                _Float16* __restrict__ dst) {
    int i = blockIdx.x * blockDim.x + threadIdx.x;   // over 3072*192 float4 chunks
    int row = i / 192, c4 = i - row * 192;
    int s = perm[row];
    half4 h; h[0] = h[1] = h[2] = h[3] = (_Float16)0.0f;
    if (s >= 0) {
        floatx4 v = ((const floatx4*)(src + (size_t)s * CC))[c4];
        h[0] = (_Float16)v[0]; h[1] = (_Float16)v[1];
        h[2] = (_Float16)v[2]; h[3] = (_Float16)v[3];
    }
    ((half4*)dst)[i] = h;
}

// W2 [768][3072] f32 -> W2c: compacted COLUMNS (perm), fp16, zero pad cols
__global__ void gatherW2_kernel(const float* __restrict__ src, const int* __restrict__ perm,
                                _Float16* __restrict__ dst) {
    int i = blockIdx.x * blockDim.x + threadIdx.x;   // over 768*768 groups of 4 cols
    int n = i / 768, j4 = (i - n * 768) * 4;
    const float* r = src + (size_t)n * HIDN;
    half4 h;
    #pragma unroll
    for (int e = 0; e < 4; e++) {
        int s = perm[j4 + e];
        h[e] = (s >= 0) ? (_Float16)r[s] : (_Float16)0.0f;
    }
    *(half4*)&dst[(size_t)n * HIDN + j4] = h;
}

// ---------------- LayerNorm (row of 768), fp32 in -> fp16 out ----------------
__global__ __launch_bounds__(256) void ln_kernel(const float* __restrict__ x,
                                                 const float* __restrict__ g,
                                                 const float* __restrict__ b,
                                                 _Float16* __restrict__ out) {
    int row = blockIdx.x;
    int t = threadIdx.x;
    const float* xr = x + (size_t)row * CC;
    float v0 = xr[t], v1 = xr[t + 256], v2 = xr[t + 512];
    float s = v0 + v1 + v2;
    float q = v0 * v0 + v1 * v1 + v2 * v2;
    #pragma unroll
    for (int m = 1; m < 64; m <<= 1) {
        s += __shfl_xor(s, m, 64);
        q += __shfl_xor(q, m, 64);
    }
    __shared__ float red[8];
    int wv = t >> 6, lane = t & 63;
    if (lane == 0) { red[wv] = s; red[wv + 4] = q; }
    __syncthreads();
    s = red[0] + red[1] + red[2] + red[3];
    q = red[4] + red[5] + red[6] + red[7];
    float mean = s * (1.0f / CC);
    float var = q * (1.0f / CC) - mean * mean;
    float rs = rsqrtf(var + 1e-5f);
    _Float16* orow = out + (size_t)row * CC;
    orow[t]       = (_Float16)((v0 - mean) * rs * g[t]       + b[t]);
    orow[t + 256] = (_Float16)((v1 - mean) * rs * g[t + 256] + b[t + 256]);
    orow[t + 512] = (_Float16)((v2 - mean) * rs * g[t + 512] + b[t + 512]);
}

// ---------------- MFMA GEMM: LDS-traffic-minimized tile (256x128, MI=8) -----
// r8 accounting: at ~6 resident 128x128 blocks the CU's LDS demand is
// 6x48KB/1570cy ~ 188 B/cyc = the LDS ceiling -> GEMM is LDS-BW-bound, and
// only tile geometry changes LDS bytes/FLOP.  This rev: wave tile 128x64
// (MI=8,NJ=4), block 256x128, 4 waves -> 36 KB per 128x128x32-equiv vs 48 KB
// (1.33x less).  Same proven 2-phase loop + swizzle.  2 waves/SIMD via
// launch_bounds (acc 128 VGPR); 2 blocks/CU (48KB LDS).
// LDS swizzle: phys 16B-chunk p of row r holds k-chunk p^((r>>2)&3);
// pre-swizzled GLOBAL src, linear gload_lds dest; read at chunk quad^((L>>2)&3)
// (wm multiple of 16 keeps the formula lane-only for all MI).
// MODE 0: compacted QKV (meta=hmeta; epilogue scatters to original head slots)
// MODE 1: out fp16 = gelu(acc + bias0); meta[0] = compacted-FFN N bound
// MODE 2: out fp32 = res + acc + bias0; kmask (hgate) skips masked-head K; meta[0]=eff.K
template <int MODE>
__global__ __launch_bounds__(256, 2) void gemm_kernel(
    const _Float16* __restrict__ A,
    const _Float16* __restrict__ W,
    const float* __restrict__ bias0,
    const float* __restrict__ bias1,
    const float* __restrict__ bias2,
    const float* __restrict__ res,
    const float* __restrict__ gate,
    const float* __restrict__ hgate,
    void* __restrict__ out0,
    void* __restrict__ out1,
    void* __restrict__ out2,
    const int* __restrict__ meta,
    const int* __restrict__ hperm,
    int M, int N, int K)
{
    // XCD-aware swizzle (GM=64 -> 8 m-stripes per XCD)
    int GN = N >> 7, GM = M >> 8;
    int f = blockIdx.x;
    int xcd = f & 7, slot = f >> 3;
    int m_idx = xcd * (GM >> 3) + slot / GN;
    int n_idx = slot - (slot / GN) * GN;
    int m0 = m_idx * 256, n0 = n_idx * 128;

    int Klen = K;
    if (MODE == 0 || MODE == 1) { if (n0 >= meta[0]) return; }  // compacted width
    if (MODE == 2 && meta) Klen = meta[0];                      // compacted K sweep

    // K-block gate mask (proj: zero A-columns from masked heads), 64-k granularity
    unsigned kmask = 0xFFFFFFFFu;
    if (MODE == 2 && hgate) {
        kmask = 0;
        for (int i = 0; i < HH; i++) kmask |= (hgate[i] > 0.0f ? 1u : 0u) << i;
    }

    __shared__ _Float16 As[2][256 * 32];   // 32KB total, row stride 32 halfs (64B)
    __shared__ _Float16 Bs[2][128 * 32];   // 16KB total
    int t = threadIdx.x;
    int lane = t & 63, w = t >> 6;
    int wm = (w >> 1) * 128, wn = (w & 1) * 64;
    int L = lane & 15, quad = lane >> 4;
    int rchunk = (quad ^ ((L >> 2) & 3)) * 8;   // swizzled k-chunk for fragment reads

    floatx4 acc[8][4];
    #pragma unroll
    for (int i = 0; i < 8; i++)
        #pragma unroll
        for (int j = 0; j < 4; j++)
            acc[i][j] = (floatx4){0.f, 0.f, 0.f, 0.f};

    // staging: physical chunk pc = issue*256 + t; row = pc>>2, kc = (pc&3)^((pc>>4)&3)
    const _Float16* agp[4];
    const _Float16* bgp[2];
    #pragma unroll
    for (int i = 0; i < 4; i++) {
        int pc = i * 256 + t;
        int row = pc >> 2;
        int kc = (pc & 3) ^ ((pc >> 4) & 3);
        agp[i] = A + (size_t)(m0 + row) * K + kc * 8;
    }
    #pragma unroll
    for (int i = 0; i < 2; i++) {
        int pc = i * 256 + t;
        int row = pc >> 2;
        int kc = (pc & 3) ^ ((pc >> 4) & 3);
        bgp[i] = W + (size_t)(n0 + row) * K + kc * 8;
    }
    unsigned wb = (unsigned)w * 512;   // wave-uniform LDS base (halfs) per issue block

    auto nextk = [&](int k0) -> int {
        if (MODE == 2)
            while (k0 < Klen && !((kmask >> ((k0 >> 6) & 31)) & 1)) k0 += 32;
        return k0;
    };
    auto stage = [&](int buf, int k0) {
        #pragma unroll
        for (int i = 0; i < 4; i++) GLOAD_LDS(agp[i] + k0, &As[buf][i * 2048 + wb]);
        #pragma unroll
        for (int i = 0; i < 2; i++) GLOAD_LDS(bgp[i] + k0, &Bs[buf][i * 2048 + wb]);
    };
    auto compute = [&](int buf) {
        half8 af[8], bf[4];
        #pragma unroll
        for (int i = 0; i < 8; i++) af[i] = *(const half8*)&As[buf][(wm + i * 16 + L) * 32 + rchunk];
        #pragma unroll
        for (int j = 0; j < 4; j++)  bf[j] = *(const half8*)&Bs[buf][(wn + j * 16 + L) * 32 + rchunk];
        #pragma unroll
        for (int i = 0; i < 8; i++)
            #pragma unroll
            for (int j = 0; j < 4; j++)
                acc[i][j] = __builtin_amdgcn_mfma_f32_16x16x32_f16(af[i], bf[j], acc[i][j], 0, 0, 0);
    };

    int kcur = nextk(0);
    if (kcur < Klen) {
        stage(0, kcur);
        int kn1 = nextk(kcur + 32);
        int kn2 = Klen;
        if (kn1 < Klen) { stage(1, kn1); kn2 = nextk(kn1 + 32); }
        int buf = 0;
        while (kn2 < Klen) {            // steady state: next tile in flight
            VMCNT_WAIT(6);              // current tile landed (6 issues/tile)
            RAW_BARRIER();
            compute(buf);
            RAW_BARRIER();              // all waves done reading buf before restage
            stage(buf, kn2);
            buf ^= 1;
            kn1 = kn2; kn2 = nextk(kn2 + 32);
        }
        if (kn1 < Klen) {               // two tiles left, both staged
            VMCNT_WAIT(6);
            RAW_BARRIER();
            compute(buf);
            buf ^= 1;
        }
        VMCNT_WAIT(0);                  // last tile
        RAW_BARRIER();
        compute(buf);
    }

    // epilogue: C row = quad*4 + r (M side), col = L (N side)  [verified m89/m91 layout]
    if (MODE == 0) {
        int segw = meta[2];
        int seg = n0 / segw;
        int cbase = n0 - seg * segw + wn;   // head-col base within segment (mult of 64)
        int ho = hperm[cbase >> 6];         // original head (uniform per wave)
        if (ho < 0) return;                 // pad head: outputs never read
        #pragma unroll
        for (int i = 0; i < 8; i++) {
            #pragma unroll
            for (int j = 0; j < 4; j++) {
                int d = j * 16 + L;         // 0..63 within head
                int ocol = ho * 64 + d;
                const float* bsel = (seg == 0) ? bias0 : (seg == 1) ? bias1 : bias2;
                float bs = bsel[ocol];
                if (seg < 2) {
                    _Float16* o = (_Float16*)((seg == 0) ? out0 : out1);
                    #pragma unroll
                    for (int r = 0; r < 4; r++) {
                        int gm = m0 + wm + i * 16 + quad * 4 + r;
                        o[(size_t)gm * CC + ocol] = (_Float16)(acc[i][j][r] + bs);
                    }
                } else {
                    int gm0 = m0 + wm + i * 16 + quad * 4;
                    int b_ = gm0 >> 10, n_ = gm0 & 1023;
                    half4 pk;
                    #pragma unroll
                    for (int r = 0; r < 4; r++) pk[r] = (_Float16)(acc[i][j][r] + bs);
                    size_t idx = ((size_t)(b_ * HH + ho) * 64 + d) * NNN + n_;
                    *(half4*)&((_Float16*)out2)[idx] = pk;
                }
            }
        }
    } else {
        #pragma unroll
        for (int i = 0; i < 8; i++) {
            #pragma unroll
            for (int j = 0; j < 4; j++) {
                int gn = n0 + wn + j * 16 + L;
                float bs = bias0[gn];
                #pragma unroll
                for (int r = 0; r < 4; r++) {
                    int gm = m0 + wm + i * 16 + quad * 4 + r;
                    float v = acc[i][j][r] + bs;
                    size_t idx = (size_t)gm * N + gn;
                    if (MODE == 1) {
                        float vv = 0.5f * v * (1.0f + erff(v * 0.70710678118f));
                        if (gate && !(gate[gn] > 0.0f)) vv = 0.0f;
                        ((_Float16*)out0)[idx] = (_Float16)vv;
                    } else {
                        ((float*)out0)[idx] = res[idx] + v;
                    }
                }
            }
        }
    }
}

// ---------------- MFMA flash attention (active heads only) ----------------
__global__ __launch_bounds__(256) void attn_kernel(
    const _Float16* __restrict__ Q,    // [b][n][h*64+d]
    const _Float16* __restrict__ Kp,   // [b][n][h*64+d]
    const _Float16* __restrict__ Vt,   // [(b*H+h)*64+d][n]
    const int* __restrict__ hmeta,
    const int* __restrict__ hperm,
    _Float16* __restrict__ Y)          // [b][n][h*64+d]
{
    int qt = blockIdx.x;
    int hc = blockIdx.y;
    int b  = blockIdx.z;
    if (hc >= hmeta[1]) return;        // only active heads do work
    int h = hperm[hc];
    int t = threadIdx.x;
    int q0 = qt * 64;
    size_t ybase = ((size_t)b * NNN + q0) * CC + h * DD;

    __shared__ _Float16 Qs[64][72];
    __shared__ _Float16 Ks[64][72];
    __shared__ _Float16 Vs[64][72];   // Vs[d][key]
    __shared__ _Float16 Ps[64][72];

    int lane = t & 63, w = t >> 6;
    int L = lane & 15, quad = lane >> 4;

    {   // stage Q tile, pre-scaled by D^-0.5 = 0.125 (exact in fp16)
        int r = t >> 2, c = (t & 3) * 16;
        const half8* src = (const half8*)(Q + ((size_t)b * NNN + q0 + r) * CC + h * DD + c);
        half8 h0 = src[0], h1 = src[1];
        #pragma unroll
        for (int e = 0; e < 8; e++) { h0[e] = h0[e] * (_Float16)0.125f; h1[e] = h1[e] * (_Float16)0.125f; }
        *(half8*)&Qs[r][c]     = h0;
        *(half8*)&Qs[r][c + 8] = h1;
    }

    floatx4 O[4];
    float m_[4], l_[4];
    #pragma unroll
    for (int i = 0; i < 4; i++) { O[i] = (floatx4){0.f,0.f,0.f,0.f}; m_[i] = -1e30f; l_[i] = 0.0f; }

    const size_t kbase = (size_t)b * NNN * CC + h * DD;
    const size_t vbase = (size_t)(b * HH + h) * DD * NNN;

    for (int kt = 0; kt < 16; ++kt) {
        int k0 = kt * 64;
        __syncthreads();
        {
            int r = t >> 2, c = (t & 3) * 16;
            const half8* ks = (const half8*)(Kp + kbase + (size_t)(k0 + r) * CC + c);
            half8 ka = ks[0], kb = ks[1];
            *(half8*)&Ks[r][c]     = ka;
            *(half8*)&Ks[r][c + 8] = kb;
            const half8* vs = (const half8*)(Vt + vbase + (size_t)r * NNN + k0 + c);
            half8 va = vs[0], vb = vs[1];
            *(half8*)&Vs[r][c]     = va;
            *(half8*)&Vs[r][c + 8] = vb;
        }
        __syncthreads();

        half8 aq0 = *(const half8*)&Qs[16 * w + L][quad * 8];
        half8 aq1 = *(const half8*)&Qs[16 * w + L][quad * 8 + 32];
        floatx4 s[4];
        #pragma unroll
        for (int j = 0; j < 4; j++) {
            half8 b0 = *(const half8*)&Ks[16 * j + L][quad * 8];
            half8 b1 = *(const half8*)&Ks[16 * j + L][quad * 8 + 32];
            floatx4 z = (floatx4){0.f,0.f,0.f,0.f};
            z = __builtin_amdgcn_mfma_f32_16x16x32_f16(aq0, b0, z, 0, 0, 0);
            z = __builtin_amdgcn_mfma_f32_16x16x32_f16(aq1, b1, z, 0, 0, 0);
            s[j] = z;
        }

        #pragma unroll
        for (int r = 0; r < 4; r++) {
            float mx = fmaxf(fmaxf(s[0][r], s[1][r]), fmaxf(s[2][r], s[3][r]));
            mx = fmaxf(mx, __shfl_xor(mx, 1, 64));
            mx = fmaxf(mx, __shfl_xor(mx, 2, 64));
            mx = fmaxf(mx, __shfl_xor(mx, 4, 64));
            mx = fmaxf(mx, __shfl_xor(mx, 8, 64));
            float mnew = fmaxf(m_[r], mx);
            float alpha = __expf(m_[r] - mnew);
            m_[r] = mnew;
            float ps = 0.0f;
            #pragma unroll
            for (int j = 0; j < 4; j++) {
                float p = __expf(s[j][r] - mnew);
                s[j][r] = p; ps += p;
                Ps[16 * w + quad * 4 + r][L + 16 * j] = (_Float16)p;
            }
            ps += __shfl_xor(ps, 1, 64);
            ps += __shfl_xor(ps, 2, 64);
            ps += __shfl_xor(ps, 4, 64);
            ps += __shfl_xor(ps, 8, 64);
            l_[r] = l_[r] * alpha + ps;
            #pragma unroll
            for (int t4 = 0; t4 < 4; t4++) O[t4][r] *= alpha;
        }
        __syncthreads();

        half8 ap0 = *(const half8*)&Ps[16 * w + L][quad * 8];
        half8 ap1 = *(const half8*)&Ps[16 * w + L][quad * 8 + 32];
        #pragma unroll
        for (int t4 = 0; t4 < 4; t4++) {
            half8 b0 = *(const half8*)&Vs[16 * t4 + L][quad * 8];
            half8 b1 = *(const half8*)&Vs[16 * t4 + L][quad * 8 + 32];
            O[t4] = __builtin_amdgcn_mfma_f32_16x16x32_f16(ap0, b0, O[t4], 0, 0, 0);
            O[t4] = __builtin_amdgcn_mfma_f32_16x16x32_f16(ap1, b1, O[t4], 0, 0, 0);
        }
    }

    __syncthreads();
    #pragma unroll
    for (int r = 0; r < 4; r++) {
        float inv = 1.0f / l_[r];
        #pragma unroll
        for (int t4 = 0; t4 < 4; t4++)
            Ps[16 * w + quad * 4 + r][16 * t4 + L] = (_Float16)(O[t4][r] * inv);
    }
    __syncthreads();
    {
        int r = t >> 2, c = (t & 3) * 16;
        half8 o0 = *(const half8*)&Ps[r][c];
        half8 o1 = *(const half8*)&Ps[r][c + 8];
        *(half8*)&Y[ybase + (size_t)r * CC + c]     = o0;
        *(half8*)&Y[ybase + (size_t)r * CC + c + 8] = o1;
    }
}

// ---------------- launch ----------------
extern "C" void kernel_launch(void* const* d_in, const int* in_sizes, int n_in,
                              void* d_out, int out_size, void* d_ws, size_t ws_size,
                              hipStream_t stream)
{
    const float* x      = (const float*)d_in[0];
    const float* ln1_g  = (const float*)d_in[1];
    const float* ln1_b  = (const float*)d_in[2];
    const float* wq     = (const float*)d_in[3];
    const float* bq     = (const float*)d_in[4];
    const float* wk     = (const float*)d_in[5];
    const float* bk     = (const float*)d_in[6];
    const float* wv     = (const float*)d_in[7];
    const float* bv     = (const float*)d_in[8];
    const float* wp     = (const float*)d_in[9];
    const float* bp     = (const float*)d_in[10];
    const float* ln2_g  = (const float*)d_in[11];
    const float* ln2_b  = (const float*)d_in[12];
    const float* w1     = (const float*)d_in[13];
    const float* b1     = (const float*)d_in[14];
    const float* w2     = (const float*)d_in[15];
    const float* b2     = (const float*)d_in[16];
    const float* gate_h = (const float*)d_in[17];
    const float* gate_f = (const float*)d_in[18];

    char* ws = (char*)d_ws;
    _Float16* WQKVc = (_Float16*)(ws + 0);        // compacted [3*Hpad*64][768] fp16
    _Float16* WPh = (_Float16*)(ws + 3538944);
    _Float16* W1c = (_Float16*)(ws + 4718592);    // compacted rows of w1
    _Float16* W2c = (_Float16*)(ws + 9437184);    // compacted cols of w2
    _Float16* XN  = (_Float16*)(ws + 14155776);
    _Float16* Qb  = (_Float16*)(ws + 39321600);
    _Float16* Kb  = (_Float16*)(ws + 64487424);
    _Float16* Vtb = (_Float16*)(ws + 89653248);   // V transposed: [(b*H+h)*64+d][n]
    _Float16* Yb  = (_Float16*)(ws + 114819072);
    float*    X1  = (float*)   (ws + 139984896);
    _Float16* XN2 = (_Float16*)(ws + 114819072);  // aliases Yb (dead after proj)
    _Float16* F1  = (_Float16*)(ws + 14155776);   // aliases XN/Q/K/Vt (dead by then)
    int*      meta = (int*)    (ws + 190316544);  // [0]=Na_pad128 [1]=Na
    int*      perm = (int*)    (ws + 190316800);  // 3072 ints
    float*    b1c  = (float*)  (ws + 190329088);  // 3072 floats
    int*      hmeta = (int*)   (ws + 190341376);  // [0]=3*Hpad*64 [1]=Ha [2]=Hpad*64
    int*      hperm = (int*)   (ws + 190341440);  // 12 ints

    // compactions
    scan_kernel<<<1, 256, 0, stream>>>(gate_f, b1, meta, perm, b1c);
    scanh_kernel<<<1, 64, 0, stream>>>(gate_h, hmeta, hperm);

    // weight converts / gathers
    gatherQKV_kernel<<<1728, 256, 0, stream>>>(wq, wk, wv, hmeta, hperm, WQKVc);
    cvt_kernel<<<576, 256, 0, stream>>>(wp, WPh, 147456);
    gatherW1_kernel<<<2304, 256, 0, stream>>>(w1, perm, W1c);
    gatherW2_kernel<<<2304, 256, 0, stream>>>(w2, perm, W2c);

    // LN1
    ln_kernel<<<ROWS, 256, 0, stream>>>(x, ln1_g, ln1_b, XN);

    // compacted QKV projection: GM=64 x GN=18 (blocks beyond 3*Hpad*64 exit)
    gemm_kernel<0><<<1152, 256, 0, stream>>>(
        XN, WQKVc, bq, bk, bv, nullptr, nullptr, nullptr, Qb, Kb, Vtb, hmeta, hperm, ROWS, 2304, CC);

    // attention (active heads only; masked heads' Y never read by proj)
    attn_kernel<<<dim3(16, HH, BB), 256, 0, stream>>>(Qb, Kb, Vtb, hmeta, hperm, Yb);

    // proj + residual -> X1 (fp32); masked-head K-blocks skipped via kmask; GM=64 x GN=6
    gemm_kernel<2><<<384, 256, 0, stream>>>(
        Yb, WPh, bp, nullptr, nullptr, x, nullptr, gate_h, X1, nullptr, nullptr, nullptr, nullptr, ROWS, CC, CC);

    // LN2
    ln_kernel<<<ROWS, 256, 0, stream>>>(X1, ln2_g, ln2_b, XN2);

    // MLP1 (compacted width Na_pad; ~half the n-blocks exit) -> F1 fp16; GM=64 x GN=24
    gemm_kernel<1><<<1536, 256, 0, stream>>>(
        XN2, W1c, b1c, nullptr, nullptr, nullptr, nullptr, nullptr, F1, nullptr, nullptr, meta, nullptr, ROWS, HIDN, CC);

    // MLP2 + residual -> out fp32 (K sweep bounded by meta[0]); GM=64 x GN=6
    gemm_kernel<2><<<384, 256, 0, stream>>>(
        F1, W2c, b2, nullptr, nullptr, X1, nullptr, nullptr, (float*)d_out, nullptr, nullptr, meta, nullptr, ROWS, CC, HIDN);
}